// Round 15
// baseline (204.165 us; speedup 1.0000x reference)
//
#include <hip/hip_runtime.h>
#include <hip/hip_bf16.h>
#include <stdint.h>

typedef __hip_bfloat16 bf16;
typedef __attribute__((ext_vector_type(8))) short v8s;   // 8 bf16 in 4 VGPRs
typedef __attribute__((ext_vector_type(4))) float v4f;   // MFMA C/D frag

__device__ __forceinline__ bf16 tob(float x) { return __float2bfloat16(x); }

// async global->LDS, 16B per lane; LDS dest must be wave-uniform base + lane*16
__device__ __forceinline__ void gload16(const void* g, void* l) {
  __builtin_amdgcn_global_load_lds(
      (const __attribute__((address_space(1))) uint32_t*)g,
      (__attribute__((address_space(3))) uint32_t*)l,
      16, 0, 0);
}

// Sum over each aligned 16-lane group via DPP (VALU pipe, no LDS crossbar).
__device__ __forceinline__ float red16(float v) {
  v += __int_as_float(__builtin_amdgcn_update_dpp(0, __float_as_int(v), 0xB1, 0xF, 0xF, true));
  v += __int_as_float(__builtin_amdgcn_update_dpp(0, __float_as_int(v), 0x4E, 0xF, 0xF, true));
  v += __int_as_float(__builtin_amdgcn_update_dpp(0, __float_as_int(v), 0x141, 0xF, 0xF, true));
  v += __int_as_float(__builtin_amdgcn_update_dpp(0, __float_as_int(v), 0x140, 0xF, 0xF, true));
  return v;
}

// ============ fused input-only preprocessing (1 launch) ============
// blocks 0..511    : h1 = relu(fea @ W_l1 + b_l1)         (8,1024), K=1024
// blocks 512..767  : gp[b,n] = fea[b] @ W_c1[5:,n] + bc1  (8,512),  K=1024
// blocks 768..1023 : W2T[n,k-swz] = bf16(W_c2[k,n])       (512,512), pre-swizzled
// block  1024      : G[g,k] = gx*Wc1[0,k] + gy*Wc1[1,k]   (16,512)
// blocks 1025..1408: fine = 0
__global__ void k_pre(const float* __restrict__ fea, const float* __restrict__ Wl1,
                      const float* __restrict__ bl1, const float* __restrict__ Wc1,
                      const float* __restrict__ bc1, const float* __restrict__ Wc2,
                      float* __restrict__ h1, float* __restrict__ gp,
                      bf16* __restrict__ WT, float* __restrict__ G,
                      float* __restrict__ fine) {
  __shared__ __align__(16) float sm[32 * 33 + 32];
  const int bid = blockIdx.x;
  if (bid < 512) {                     // ---- lin1 ----
    float* red = sm;
    const int nl = threadIdx.x & 15, ks = threadIdx.x >> 4;
    const int o = bid * 16 + nl;
    const int b = o >> 10, n = o & 1023;
    const float* fr = fea + (b << 10) + ks * 64;
    const float* wp = Wl1 + (size_t)(ks * 64) * 1024 + n;
    float acc = 0.f;
#pragma unroll 8
    for (int j = 0; j < 64; ++j)
      acc = fmaf(fr[j], wp[(size_t)j * 1024], acc);
    red[threadIdx.x] = acc;
    __syncthreads();
    if (threadIdx.x < 16) {
      float s = bl1[n];
#pragma unroll
      for (int i = 0; i < 16; ++i) s += red[i * 16 + threadIdx.x];
      h1[o] = fmaxf(s, 0.f);
    }
  } else if (bid < 768) {              // ---- gp ----
    float* red = sm;
    const int nl = threadIdx.x & 15, ks = threadIdx.x >> 4;
    const int o = (bid - 512) * 16 + nl;
    const int b = o >> 9, n = o & 511;
    const float* fr = fea + (b << 10) + ks * 64;
    const float* wp = Wc1 + (size_t)(5 + ks * 64) * 512 + n;
    float acc = 0.f;
#pragma unroll 8
    for (int j = 0; j < 64; ++j)
      acc = fmaf(fr[j], wp[(size_t)j * 512], acc);
    red[threadIdx.x] = acc;
    __syncthreads();
    if (threadIdx.x < 16) {
      float s = bc1[n];
#pragma unroll
      for (int i = 0; i < 16; ++i) s += red[i * 16 + threadIdx.x];
      gp[o] = s;
    }
  } else if (bid < 1024) {             // ---- w2t (pre-swizzled transpose) ----
    float (*tile)[33] = (float(*)[33])sm;
    const int bb = bid - 768;
    int bx = bb & 15, by = bb >> 4;
    int c = threadIdx.x & 31, r8 = threadIdx.x >> 5;
#pragma unroll
    for (int i = 0; i < 4; ++i) {
      int r = r8 + i * 8;
      tile[r][c] = Wc2[(by * 32 + r) * 512 + bx * 32 + c];
    }
    __syncthreads();
#pragma unroll
    for (int i = 0; i < 4; ++i) {
      int r = r8 + i * 8;
      int n = bx * 32 + r;                       // output row (conv2 in-chan)
      int k = by * 32 + c;                       // original k
      int s = (c >> 3) & 3;                      // 16B slot in 64B K-block
      int ks = (k & ~24) | (((s ^ ((n >> 1) & 3)) & 3) << 3);
      WT[(size_t)n * 512 + ks] = tob(tile[c][r]);
    }
  } else if (bid == 1024) {            // ---- grid table ----
    for (int e = threadIdx.x; e < 8192; e += 256) {
      int g = e >> 9, k = e & 511;
      const float gx = -0.05f + (float)(g & 3) * (0.1f / 3.0f);
      const float gy = -0.05f + (float)(g >> 2) * (0.1f / 3.0f);
      G[e] = fmaf(gy, Wc1[512 + k], gx * Wc1[k]);
    }
  } else {                             // ---- zero fine (393216 floats) ----
    const int i = ((bid - 1025) * 256 + threadIdx.x) * 4;
    *(float4*)(fine + i) = (float4){0.f, 0.f, 0.f, 0.f};
  }
}

// x = h1 @ W_l2 + b_l2   (8,3072), K=1024 -> xf (ws) + xout (d_out)
// One block per 16-n group, FULL K=1024 in block (no cross-block combine).
// W_l2 read exactly once. h1 (32 KB) in LDS, broadcast. 192 blocks x 256 thr.
__global__ void k_lin2(const float* __restrict__ h1, const float* __restrict__ W,
                       const float* __restrict__ bias, float* __restrict__ xf,
                       float* __restrict__ xout) {
  __shared__ float h1s[8][1024];         // 32 KB
  __shared__ float red[16][16][9];       // 9 KB [ks][nl][b], pad 9: bank spread
  const int t = threadIdx.x;             // 256
  const int n0 = blockIdx.x * 16;        // 192 blocks
  for (int i = t; i < 8192; i += 256)    // h1 is (8,1024) contiguous
    ((float*)h1s)[i] = h1[i];
  __syncthreads();
  const int nl = t & 15, ks = t >> 4;
  const int n = n0 + nl;
  float acc[8] = {0.f, 0.f, 0.f, 0.f, 0.f, 0.f, 0.f, 0.f};
  const float* wp = W + (size_t)(ks * 64) * 3072 + n;
#pragma unroll 8
  for (int j = 0; j < 64; ++j) {
    float wv = wp[(size_t)j * 3072];
    const float* hk = &h1s[0][ks * 64 + j];
#pragma unroll
    for (int b = 0; b < 8; ++b) acc[b] = fmaf(hk[b * 1024], wv, acc[b]);
  }
#pragma unroll
  for (int b = 0; b < 8; ++b) red[ks][nl][b] = acc[b];
  __syncthreads();
  if (t < 128) {                         // 128 outputs: (nn, b)
    const int nn = t & 15, b = t >> 4;
    float s = bias[n0 + nn];
#pragma unroll
    for (int i = 0; i < 16; ++i) s += red[i][nn][b];
    const int o = b * 3072 + n0 + nn;
    xf[o] = s;
    xout[o] = s;
  }
}

// ============ fused conv1+conv2 GEMM + conv3 epilogue ============
// ROUND-15: A-fragments computed IN-REGISTER; the As LDS round-trip (write 8K
// + 4x re-read 32K + stage P-read 16K per kt) is deleted. Why valid: the A
// frag mapping is known -- lane (q,lm), wave w, frag mi needs row
// wm+mi*16+lm, k=kt*32+q*8..+8; g=row&15=lm (wm,mi*16 mult of 16) and the P
// row (w>>2)*4+mi is WAVE-UNIFORM -> P reads are broadcast ds_read_b128
// (~free), G is one 32B L1 load/lane/kt (row lm), prefetched one phase ahead
// (r8 loadG pattern, issued at END of phase so the next barrier drains it).
// Produced af values are BIT-IDENTICAL to the old As path (same f32 add,
// relu, single bf16 rounding) -- zero precision delta. A-compute VALU is 4x
// duplicated across n-waves (+~56 VALU/lane/kt): VALU was not binding.
// LDS/kt: 104K -> ~52K; measured b128 throughput ceiling ~85 B/cyc (m134)
// put the old kernel at ~78% of practical LDS BW -- this halves the queue.
// Ordering SAFETY (r9/r10 class): Bs frag reads remain AFTER stage() in
// program order (unchanged); Ps is read-only after the prologue barrier (no
// DMA ever writes it -> no race surface). stage() is now 2 gload16s only.
// LAUNCH-BOUNDS RULE (r1/r4): (512,6) truncates VGPR -> spill disaster. Keep
// (512,4). Spill fingerprint: WRITE_SIZE >> FETCH blowup (r13) -> revert.
// Structure: 2048 blocks x 512 thr; rows m0..m0+127, N-half nblk*256..+255,
// K=512, BK=32; LDS ~54.5K -> 2 blocks/CU (regs bind at 4 waves/SIMD).
// B via gload16 from pre-swizzled W2T, qs-swizzled frag reads (conflict-free);
// epilogue: DPP 16-lane reduce -> per-n-wave facc4 slices -> global atomicAdd.
__global__ __launch_bounds__(512, 4)
void k_gemm(const bf16* __restrict__ W2T, const float* __restrict__ gp,
            const float* __restrict__ G, const float* __restrict__ Wc1,
            const float* __restrict__ xf, const float* __restrict__ bc2,
            const float* __restrict__ Wc3, const float* __restrict__ bc3,
            float* __restrict__ fine) {
  __shared__ __align__(16) bf16 Bs[2][256 * 32];   // 2 x 16 KB
  __shared__ __align__(16) float Ps[8][512];       // 16 KB
  __shared__ float facc4[4][128][3];               // 6 KB, slice per n-wave
  const int t = threadIdx.x;
  const int mblk = blockIdx.x >> 1, nblk = blockIdx.x & 1;
  const int m0 = mblk * 128;
  const int w = t >> 6, l = t & 63, q = l >> 4, lm = l & 15;
  const int wm = (w >> 2) * 64;          // wave output-row base (0 or 64)
  const int wn = (w & 3) * 64;           // wave output-col base within N-half
  const int qs = (q ^ ((lm >> 1) & 3)) << 4;  // swizzled 16B slot, B frag reads
  const int b = m0 >> 14;                // batch, uniform per block

  // ---- P prologue: Ps[cl][k] = gp[b][k] + x·Wc1[2:5][k], 8 elems/thread ----
  {
    const int cl = t >> 6;               // local coarse point 0..7
    const int k8 = (t & 63) * 8;
    const int cglob = ((m0 & 16383) >> 4) + cl;
    const float* xq = xf + (b * 1024 + cglob) * 3;
    const float x0 = xq[0], x1 = xq[1], x2 = xq[2];
    const float* gpb = gp + (b << 9) + k8;
    float4 gv0 = *(const float4*)(gpb);
    float4 gv1 = *(const float4*)(gpb + 4);
    float4 w20 = *(const float4*)(Wc1 + 2 * 512 + k8);
    float4 w21 = *(const float4*)(Wc1 + 2 * 512 + k8 + 4);
    float4 w30 = *(const float4*)(Wc1 + 3 * 512 + k8);
    float4 w31 = *(const float4*)(Wc1 + 3 * 512 + k8 + 4);
    float4 w40 = *(const float4*)(Wc1 + 4 * 512 + k8);
    float4 w41 = *(const float4*)(Wc1 + 4 * 512 + k8 + 4);
    float4 r0, r1;
#pragma unroll
    for (int j = 0; j < 4; ++j) {
      ((float*)&r0)[j] = fmaf(x2, ((const float*)&w40)[j],
                         fmaf(x1, ((const float*)&w30)[j],
                         fmaf(x0, ((const float*)&w20)[j], ((const float*)&gv0)[j])));
      ((float*)&r1)[j] = fmaf(x2, ((const float*)&w41)[j],
                         fmaf(x1, ((const float*)&w31)[j],
                         fmaf(x0, ((const float*)&w21)[j], ((const float*)&gv1)[j])));
    }
    *(float4*)&Ps[cl][k8] = r0;
    *(float4*)&Ps[cl][k8 + 4] = r1;
  }

  // ---- B staging role: wave stages rows [w*32, w*32+32), 2 gload16/thread ----
  const char* bsrc = (const char*)W2T +
      (size_t)(nblk * 256 + w * 32 + (l >> 2)) * 1024 + (l & 3) * 16;
  char* bdst = (char*)Bs + w * 2048 + l * 16;      // + buf*16384 + i*1024

  // ---- A-direct-compute sources ----
  const float* grow = G + (lm << 9);     // G row lm (= row&15 for all frags)
  const float* pbase = Ps[(w >> 2) * 4]; // P rows (w>>2)*4 + mi, wave-uniform

  v4f acc[4][4];
#pragma unroll
  for (int mi = 0; mi < 4; ++mi)
#pragma unroll
    for (int ni = 0; ni < 4; ++ni) acc[mi][ni] = (v4f){0.f, 0.f, 0.f, 0.f};

  // G prefetch registers: hold G(kt) across the previous phase; the barrier's
  // vmcnt(0) drains them, so zero exposed latency at first use.
  float4 ga0, ga1;
  auto loadG = [&](int kt) {
    const int kk = kt * 32 + q * 8;
    ga0 = *(const float4*)(grow + kk);
    ga1 = *(const float4*)(grow + kk + 4);
  };
  auto stage = [&](int kt, int buf) {    // B only: 2 async gload16
    const char* src = bsrc + kt * 64;
    char* dst = bdst + buf * 16384;
    gload16(src, dst);
    gload16(src + 16384, dst + 1024);    // +16 rows
  };

  loadG(0);
  __syncthreads();                       // Ps visible to all waves
  stage(0, 0);

#pragma unroll 2
  for (int kt = 0; kt < 16; ++kt) {
    const int buf = kt & 1;
    __syncthreads();                     // stage(kt,buf) + loadG(kt) complete
    if (kt < 15) stage(kt + 1, buf ^ 1); // prefetch next B tile (other buffer)
    const char* bb = (const char*)Bs + buf * 16384;
    v8s bfr[4];
#pragma unroll
    for (int ni = 0; ni < 4; ++ni)
      bfr[ni] = *(const v8s*)(bb + (wn + ni * 16 + lm) * 64 + qs);
    const int kk = kt * 32 + q * 8;
#pragma unroll
    for (int mi = 0; mi < 4; ++mi) {
      // A frag in-register: relu(P[row][k] + G[lm][k]) -> bf16x8.
      const float* pr = pbase + mi * 512 + kk;   // wave-uniform addr: broadcast
      float4 p0 = *(const float4*)(pr);
      float4 p1 = *(const float4*)(pr + 4);
      union { bf16 h[8]; v8s v; } af;
#pragma unroll
      for (int j = 0; j < 4; ++j) {
        af.h[j]     = tob(fmaxf(((const float*)&p0)[j] + ((const float*)&ga0)[j], 0.f));
        af.h[4 + j] = tob(fmaxf(((const float*)&p1)[j] + ((const float*)&ga1)[j], 0.f));
      }
#pragma unroll
      for (int ni = 0; ni < 4; ++ni)
        acc[mi][ni] = __builtin_amdgcn_mfma_f32_16x16x32_bf16(af.v, bfr[ni], acc[mi][ni], 0, 0, 0);
    }
    if (kt < 15) loadG(kt + 1);          // end of phase: next barrier drains it
  }

  // ---- epilogue: h2 = relu(acc + b_c2); fine partials via Wc3 ----
  float part[4][4][3];
#pragma unroll
  for (int mi = 0; mi < 4; ++mi)
#pragma unroll
    for (int r = 0; r < 4; ++r) { part[mi][r][0] = 0.f; part[mi][r][1] = 0.f; part[mi][r][2] = 0.f; }
#pragma unroll
  for (int ni = 0; ni < 4; ++ni) {
    const int n = nblk * 256 + wn + ni * 16 + lm;
    const float bv = bc2[n];
    const float w30 = Wc3[n * 3 + 0];
    const float w31 = Wc3[n * 3 + 1];
    const float w32 = Wc3[n * 3 + 2];
#pragma unroll
    for (int mi = 0; mi < 4; ++mi)
#pragma unroll
      for (int r = 0; r < 4; ++r) {
        float v = fmaxf(acc[mi][ni][r] + bv, 0.f);
        part[mi][r][0] = fmaf(v, w30, part[mi][r][0]);
        part[mi][r][1] = fmaf(v, w31, part[mi][r][1]);
        part[mi][r][2] = fmaf(v, w32, part[mi][r][2]);
      }
  }
  // Per-n-wave slice: each (slice,row,j) written by exactly one lane, once ->
  // plain ds_write (no atomics, no zero-init).
#pragma unroll
  for (int mi = 0; mi < 4; ++mi)
#pragma unroll
    for (int r = 0; r < 4; ++r)
#pragma unroll
      for (int j = 0; j < 3; ++j) {
        float v = red16(part[mi][r][j]);   // DPP 16-lane sum (lm group)
        if (lm == 0) facc4[w & 3][wm + mi * 16 + q * 4 + r][j] = v;
      }
  __syncthreads();
  if (t < 128) {
    const int mm = m0 + t;
    float* fp = fine + (size_t)mm * 3;
    float base[3] = {0.f, 0.f, 0.f};
    if (nblk == 0) {
      const int bb2 = mm >> 14, cc = (mm & 16383) >> 4;
      const float* xq = xf + (bb2 * 1024 + cc) * 3;
#pragma unroll
      for (int j = 0; j < 3; ++j) base[j] = bc3[j] + xq[j];
    }
#pragma unroll
    for (int j = 0; j < 3; ++j) {
      float s = facc4[0][t][j] + facc4[1][t][j] + facc4[2][t][j] + facc4[3][t][j];
      atomicAdd(&fp[j], s + base[j]);
    }
  }
}

extern "C" void kernel_launch(void* const* d_in, const int* in_sizes, int n_in,
                              void* d_out, int out_size, void* d_ws, size_t ws_size,
                              hipStream_t stream) {
  const float* fea = (const float*)d_in[0];
  const float* Wl1 = (const float*)d_in[1];
  const float* bl1 = (const float*)d_in[2];
  const float* Wl2 = (const float*)d_in[3];
  const float* bl2 = (const float*)d_in[4];
  const float* Wc1 = (const float*)d_in[5];
  const float* bc1 = (const float*)d_in[6];
  const float* Wc2 = (const float*)d_in[7];
  const float* bc2 = (const float*)d_in[8];
  const float* Wc3 = (const float*)d_in[9];
  const float* bc3 = (const float*)d_in[10];
  float* xout = (float*)d_out;                // (8,1024,3)
  float* fine = (float*)d_out + 24576;        // (8,16384,3)
  char* ws = (char*)d_ws;
  float* h1  = (float*)ws;                    // 32 KB
  float* xf  = (float*)(ws + 32768);          // 96 KB
  float* gp  = (float*)(ws + 131072);         // 16 KB
  bf16*  W2T = (bf16*)(ws + 147456);          // 512 KB
  float* G   = (float*)(ws + 671744);         // 32 KB

  k_pre<<<1409, 256, 0, stream>>>(fea, Wl1, bl1, Wc1, bc1, Wc2, h1, gp, W2T, G, fine);
  k_lin2<<<192, 256, 0, stream>>>(h1, Wl2, bl2, xf, xout);
  k_gemm<<<2048, 512, 0, stream>>>(W2T, gp, G, Wc1, xf, bc2, Wc3, bc3, fine);
}

// Round 16
// 173.495 us; speedup vs baseline: 1.1768x; 1.1768x over previous
//
#include <hip/hip_runtime.h>
#include <hip/hip_bf16.h>
#include <stdint.h>

typedef __hip_bfloat16 bf16;
typedef __attribute__((ext_vector_type(8))) short v8s;   // 8 bf16 in 4 VGPRs
typedef __attribute__((ext_vector_type(4))) float v4f;   // MFMA C/D frag

__device__ __forceinline__ bf16 tob(float x) { return __float2bfloat16(x); }

// async global->LDS, 16B per lane; LDS dest must be wave-uniform base + lane*16
__device__ __forceinline__ void gload16(const void* g, void* l) {
  __builtin_amdgcn_global_load_lds(
      (const __attribute__((address_space(1))) uint32_t*)g,
      (__attribute__((address_space(3))) uint32_t*)l,
      16, 0, 0);
}

// Sum over each aligned 16-lane group via DPP (VALU pipe, no LDS crossbar).
__device__ __forceinline__ float red16(float v) {
  v += __int_as_float(__builtin_amdgcn_update_dpp(0, __float_as_int(v), 0xB1, 0xF, 0xF, true));
  v += __int_as_float(__builtin_amdgcn_update_dpp(0, __float_as_int(v), 0x4E, 0xF, 0xF, true));
  v += __int_as_float(__builtin_amdgcn_update_dpp(0, __float_as_int(v), 0x141, 0xF, 0xF, true));
  v += __int_as_float(__builtin_amdgcn_update_dpp(0, __float_as_int(v), 0x140, 0xF, 0xF, true));
  return v;
}

// ============ fused input-only preprocessing (1 launch) ============
// blocks 0..511    : h1 = relu(fea @ W_l1 + b_l1)         (8,1024), K=1024
// blocks 512..767  : gp[b,n] = fea[b] @ W_c1[5:,n] + bc1  (8,512),  K=1024
// blocks 768..1023 : W2T[n,k-swz] = bf16(W_c2[k,n])       (512,512), pre-swizzled
// block  1024      : G[g,k] = gx*Wc1[0,k] + gy*Wc1[1,k]   (16,512)
// blocks 1025..1408: fine = 0
__global__ void k_pre(const float* __restrict__ fea, const float* __restrict__ Wl1,
                      const float* __restrict__ bl1, const float* __restrict__ Wc1,
                      const float* __restrict__ bc1, const float* __restrict__ Wc2,
                      float* __restrict__ h1, float* __restrict__ gp,
                      bf16* __restrict__ WT, float* __restrict__ G,
                      float* __restrict__ fine) {
  __shared__ __align__(16) float sm[32 * 33 + 32];
  const int bid = blockIdx.x;
  if (bid < 512) {                     // ---- lin1 ----
    float* red = sm;
    const int nl = threadIdx.x & 15, ks = threadIdx.x >> 4;
    const int o = bid * 16 + nl;
    const int b = o >> 10, n = o & 1023;
    const float* fr = fea + (b << 10) + ks * 64;
    const float* wp = Wl1 + (size_t)(ks * 64) * 1024 + n;
    float acc = 0.f;
#pragma unroll 8
    for (int j = 0; j < 64; ++j)
      acc = fmaf(fr[j], wp[(size_t)j * 1024], acc);
    red[threadIdx.x] = acc;
    __syncthreads();
    if (threadIdx.x < 16) {
      float s = bl1[n];
#pragma unroll
      for (int i = 0; i < 16; ++i) s += red[i * 16 + threadIdx.x];
      h1[o] = fmaxf(s, 0.f);
    }
  } else if (bid < 768) {              // ---- gp ----
    float* red = sm;
    const int nl = threadIdx.x & 15, ks = threadIdx.x >> 4;
    const int o = (bid - 512) * 16 + nl;
    const int b = o >> 9, n = o & 511;
    const float* fr = fea + (b << 10) + ks * 64;
    const float* wp = Wc1 + (size_t)(5 + ks * 64) * 512 + n;
    float acc = 0.f;
#pragma unroll 8
    for (int j = 0; j < 64; ++j)
      acc = fmaf(fr[j], wp[(size_t)j * 512], acc);
    red[threadIdx.x] = acc;
    __syncthreads();
    if (threadIdx.x < 16) {
      float s = bc1[n];
#pragma unroll
      for (int i = 0; i < 16; ++i) s += red[i * 16 + threadIdx.x];
      gp[o] = s;
    }
  } else if (bid < 1024) {             // ---- w2t (pre-swizzled transpose) ----
    float (*tile)[33] = (float(*)[33])sm;
    const int bb = bid - 768;
    int bx = bb & 15, by = bb >> 4;
    int c = threadIdx.x & 31, r8 = threadIdx.x >> 5;
#pragma unroll
    for (int i = 0; i < 4; ++i) {
      int r = r8 + i * 8;
      tile[r][c] = Wc2[(by * 32 + r) * 512 + bx * 32 + c];
    }
    __syncthreads();
#pragma unroll
    for (int i = 0; i < 4; ++i) {
      int r = r8 + i * 8;
      int n = bx * 32 + r;                       // output row (conv2 in-chan)
      int k = by * 32 + c;                       // original k
      int s = (c >> 3) & 3;                      // 16B slot in 64B K-block
      int ks = (k & ~24) | (((s ^ ((n >> 1) & 3)) & 3) << 3);
      WT[(size_t)n * 512 + ks] = tob(tile[c][r]);
    }
  } else if (bid == 1024) {            // ---- grid table ----
    for (int e = threadIdx.x; e < 8192; e += 256) {
      int g = e >> 9, k = e & 511;
      const float gx = -0.05f + (float)(g & 3) * (0.1f / 3.0f);
      const float gy = -0.05f + (float)(g >> 2) * (0.1f / 3.0f);
      G[e] = fmaf(gy, Wc1[512 + k], gx * Wc1[k]);
    }
  } else {                             // ---- zero fine (393216 floats) ----
    const int i = ((bid - 1025) * 256 + threadIdx.x) * 4;
    *(float4*)(fine + i) = (float4){0.f, 0.f, 0.f, 0.f};
  }
}

// x = h1 @ W_l2 + b_l2   (8,3072), K=1024 -> xf (ws) + xout (d_out)
// One block per 16-n group, FULL K=1024 in block (no cross-block combine).
// W_l2 read exactly once. h1 (32 KB) in LDS, broadcast. 192 blocks x 256 thr.
__global__ void k_lin2(const float* __restrict__ h1, const float* __restrict__ W,
                       const float* __restrict__ bias, float* __restrict__ xf,
                       float* __restrict__ xout) {
  __shared__ float h1s[8][1024];         // 32 KB
  __shared__ float red[16][16][9];       // 9 KB [ks][nl][b], pad 9: bank spread
  const int t = threadIdx.x;             // 256
  const int n0 = blockIdx.x * 16;        // 192 blocks
  for (int i = t; i < 8192; i += 256)    // h1 is (8,1024) contiguous
    ((float*)h1s)[i] = h1[i];
  __syncthreads();
  const int nl = t & 15, ks = t >> 4;
  const int n = n0 + nl;
  float acc[8] = {0.f, 0.f, 0.f, 0.f, 0.f, 0.f, 0.f, 0.f};
  const float* wp = W + (size_t)(ks * 64) * 3072 + n;
#pragma unroll 8
  for (int j = 0; j < 64; ++j) {
    float wv = wp[(size_t)j * 3072];
    const float* hk = &h1s[0][ks * 64 + j];
#pragma unroll
    for (int b = 0; b < 8; ++b) acc[b] = fmaf(hk[b * 1024], wv, acc[b]);
  }
#pragma unroll
  for (int b = 0; b < 8; ++b) red[ks][nl][b] = acc[b];
  __syncthreads();
  if (t < 128) {                         // 128 outputs: (nn, b)
    const int nn = t & 15, b = t >> 4;
    float s = bias[n0 + nn];
#pragma unroll
    for (int i = 0; i < 16; ++i) s += red[i][nn][b];
    const int o = b * 3072 + n0 + nn;
    xf[o] = s;
    xout[o] = s;
  }
}

// ============ fused conv1+conv2 GEMM + conv3 epilogue ============
// ROUND-16: byte-exact restore of the round-12/14 kernel (best passing:
// k_gemm 88.5-89.3 us, 776 TF effective incl. fused conv1 A-compute; total
// 173.5-174.5 us, twice-reproduced).
// SEARCH-SPACE CLOSURE (all measured):
//  - occupancy ↑: register wall (r1/r4: (512,6) truncation-spill; r13: +16
//    live VGPR prefetch spill; 64-AGPR acc caps 4 waves/SIMD at VGPR<=128).
//  - LDS-traffic ↓ via in-register A (r15): -50% LDS but 4x duplicated
//    A-VALU + serial add/max/cvt chain ahead of each MFMA -> 122 us. LDS BW
//    was NOT binding; r14 is barrier-lockstep-bound (no pipe saturated).
//  - B-from-global: r7 (demand: latency-exposed, 162 us), r13 (prefetched:
//    spill, 322 us).
//  - deeper prefetch: r5/r8 null -- every VMEM drain already phase-amortized.
//  - frag-read reorder ahead of stage: r9/r10 miscompile (compiler scheduling
//    of ds_read vs global_load_lds issue) -- forbidden.
//  - epilogue: de-contended (r12, kept: facc4 slices, DPP reduce).
// Structure: 2048 blocks x 512 thr; rows m0..m0+127, N-half nblk*256..+255,
// K=512, BK=32; LDS 71680 -> 2 blocks/CU. Ps prologue (P in LDS); G reg-
// prefetched one phase ahead; B via gload16 from pre-swizzled W2T; A k-slot
// swizzle (row>>1)&3 write+read (bank-conflict-free, ~0 measured).
__global__ __launch_bounds__(512, 4)
void k_gemm(const bf16* __restrict__ W2T, const float* __restrict__ gp,
            const float* __restrict__ G, const float* __restrict__ Wc1,
            const float* __restrict__ xf, const float* __restrict__ bc2,
            const float* __restrict__ Wc3, const float* __restrict__ bc3,
            float* __restrict__ fine) {
  __shared__ __align__(16) bf16 As[2][128 * 32];   // 2 x 8 KB
  __shared__ __align__(16) bf16 Bs[2][256 * 32];   // 2 x 16 KB
  __shared__ __align__(16) float Ps[8][512];       // 16 KB
  __shared__ float facc4[4][128][3];               // 6 KB, slice per n-wave
  const int t = threadIdx.x;
  const int mblk = blockIdx.x >> 1, nblk = blockIdx.x & 1;
  const int m0 = mblk * 128;
  const int w = t >> 6, l = t & 63, q = l >> 4, lm = l & 15;
  const int wm = (w >> 2) * 64;          // wave output-row base (0 or 64)
  const int wn = (w & 3) * 64;           // wave output-col base within N-half
  const int qs = (q ^ ((lm >> 1) & 3)) << 4;  // swizzled 16B slot for frag reads

  // ---- A-compute role: thread -> (row arow, k-subgroup cg of 8) ----
  const int arow = t >> 2, cg = t & 3;
  const int m = m0 + arow;
  const int b = m >> 14;                 // batch, uniform per block
  const int f = m & 16383;
  const int g = f & 15;
  const float* gr = G + (g << 9);                       // G row (512 f32)
  const float* pl = Ps[arow >> 4];                      // local P row in LDS
  char* awr = (char*)As + arow * 64 + ((cg ^ ((arow >> 1) & 3)) << 4); // + buf*8192

  // ---- P prologue: Ps[cl][k] = gp[b][k] + x·Wc1[2:5][k], 8 elems/thread ----
  {
    const int cl = t >> 6;               // local coarse point 0..7
    const int k8 = (t & 63) * 8;
    const int cglob = ((m0 & 16383) >> 4) + cl;
    const float* xq = xf + (b * 1024 + cglob) * 3;
    const float x0 = xq[0], x1 = xq[1], x2 = xq[2];
    const float* gpb = gp + (b << 9) + k8;
    float4 gv0 = *(const float4*)(gpb);
    float4 gv1 = *(const float4*)(gpb + 4);
    float4 w20 = *(const float4*)(Wc1 + 2 * 512 + k8);
    float4 w21 = *(const float4*)(Wc1 + 2 * 512 + k8 + 4);
    float4 w30 = *(const float4*)(Wc1 + 3 * 512 + k8);
    float4 w31 = *(const float4*)(Wc1 + 3 * 512 + k8 + 4);
    float4 w40 = *(const float4*)(Wc1 + 4 * 512 + k8);
    float4 w41 = *(const float4*)(Wc1 + 4 * 512 + k8 + 4);
    float4 r0, r1;
#pragma unroll
    for (int j = 0; j < 4; ++j) {
      ((float*)&r0)[j] = fmaf(x2, ((const float*)&w40)[j],
                         fmaf(x1, ((const float*)&w30)[j],
                         fmaf(x0, ((const float*)&w20)[j], ((const float*)&gv0)[j])));
      ((float*)&r1)[j] = fmaf(x2, ((const float*)&w41)[j],
                         fmaf(x1, ((const float*)&w31)[j],
                         fmaf(x0, ((const float*)&w21)[j], ((const float*)&gv1)[j])));
    }
    *(float4*)&Ps[cl][k8] = r0;
    *(float4*)&Ps[cl][k8 + 4] = r1;
  }

  // ---- B staging role: wave stages rows [w*32, w*32+32), 2 gload16/thread ----
  const char* bsrc = (const char*)W2T +
      (size_t)(nblk * 256 + w * 32 + (l >> 2)) * 1024 + (l & 3) * 16;
  char* bdst = (char*)Bs + w * 2048 + l * 16;      // + buf*16384 + i*1024

  v4f acc[4][4];
#pragma unroll
  for (int mi = 0; mi < 4; ++mi)
#pragma unroll
    for (int ni = 0; ni < 4; ++ni) acc[mi][ni] = (v4f){0.f, 0.f, 0.f, 0.f};

  // G prefetch registers: hold G(kt+1) across phase kt (neutral, kept from r8)
  float4 ga0, ga1;
  auto loadG = [&](int kt) {
    const int kk = kt * 32 + cg * 8;
    ga0 = *(const float4*)(gr + kk);
    ga1 = *(const float4*)(gr + kk + 4);
  };
  auto stage = [&](int kt, int buf) {
    // B: async loads in flight first
    const char* src = bsrc + kt * 64;
    char* dst = bdst + buf * 16384;
    gload16(src, dst);
    gload16(src + 16384, dst + 1024);    // +16 rows
    // A: relu(P + G); P broadcast ds_read, G from registers loaded LAST phase
    const int kk = kt * 32 + cg * 8;
    float4 p0 = *(const float4*)(pl + kk);
    float4 p1 = *(const float4*)(pl + kk + 4);
    union { bf16 h[8]; uint4 u; } o;
#pragma unroll
    for (int j = 0; j < 4; ++j) {
      o.h[j]     = tob(fmaxf(((const float*)&p0)[j] + ((const float*)&ga0)[j], 0.f));
      o.h[4 + j] = tob(fmaxf(((const float*)&p1)[j] + ((const float*)&ga1)[j], 0.f));
    }
    *(uint4*)(awr + buf * 8192) = o.u;
  };

  loadG(0);
  __syncthreads();                       // Ps visible to all waves
  stage(0, 0);
  loadG(1);                              // in flight across phase 0

#pragma unroll 2
  for (int kt = 0; kt < 16; ++kt) {
    const int buf = kt & 1;
    __syncthreads();                     // stage(kt,buf) complete on all waves
    if (kt < 15) {
      stage(kt + 1, buf ^ 1);            // consumes G(kt+1) prefetched regs
      if (kt < 14) loadG(kt + 2);        // issue AFTER gload16s: in-order vmcnt
    }
    const char* ab = (const char*)As + buf * 8192;
    const char* bb = (const char*)Bs + buf * 16384;
    v8s af[4], bfr[4];
#pragma unroll
    for (int mi = 0; mi < 4; ++mi)
      af[mi] = *(const v8s*)(ab + (wm + mi * 16 + lm) * 64 + qs);
#pragma unroll
    for (int ni = 0; ni < 4; ++ni)
      bfr[ni] = *(const v8s*)(bb + (wn + ni * 16 + lm) * 64 + qs);
#pragma unroll
    for (int mi = 0; mi < 4; ++mi)
#pragma unroll
      for (int ni = 0; ni < 4; ++ni)
        acc[mi][ni] = __builtin_amdgcn_mfma_f32_16x16x32_bf16(af[mi], bfr[ni], acc[mi][ni], 0, 0, 0);
  }

  // ---- epilogue: h2 = relu(acc + b_c2); fine partials via Wc3 ----
  float part[4][4][3];
#pragma unroll
  for (int mi = 0; mi < 4; ++mi)
#pragma unroll
    for (int r = 0; r < 4; ++r) { part[mi][r][0] = 0.f; part[mi][r][1] = 0.f; part[mi][r][2] = 0.f; }
#pragma unroll
  for (int ni = 0; ni < 4; ++ni) {
    const int n = nblk * 256 + wn + ni * 16 + lm;
    const float bv = bc2[n];
    const float w30 = Wc3[n * 3 + 0];
    const float w31 = Wc3[n * 3 + 1];
    const float w32 = Wc3[n * 3 + 2];
#pragma unroll
    for (int mi = 0; mi < 4; ++mi)
#pragma unroll
      for (int r = 0; r < 4; ++r) {
        float v = fmaxf(acc[mi][ni][r] + bv, 0.f);
        part[mi][r][0] = fmaf(v, w30, part[mi][r][0]);
        part[mi][r][1] = fmaf(v, w31, part[mi][r][1]);
        part[mi][r][2] = fmaf(v, w32, part[mi][r][2]);
      }
  }
  // Per-n-wave slice: each (slice,row,j) written by exactly one lane, once ->
  // plain ds_write (was: 192 contended LDS atomicAdds per wave).
#pragma unroll
  for (int mi = 0; mi < 4; ++mi)
#pragma unroll
    for (int r = 0; r < 4; ++r)
#pragma unroll
      for (int j = 0; j < 3; ++j) {
        float v = red16(part[mi][r][j]);   // DPP 16-lane sum (lm group)
        if (lm == 0) facc4[w & 3][wm + mi * 16 + q * 4 + r][j] = v;
      }
  __syncthreads();
  if (t < 128) {
    const int mm = m0 + t;
    float* fp = fine + (size_t)mm * 3;
    float base[3] = {0.f, 0.f, 0.f};
    if (nblk == 0) {
      const int bb2 = mm >> 14, cc = (mm & 16383) >> 4;
      const float* xq = xf + (bb2 * 1024 + cc) * 3;
#pragma unroll
      for (int j = 0; j < 3; ++j) base[j] = bc3[j] + xq[j];
    }
#pragma unroll
    for (int j = 0; j < 3; ++j) {
      float s = facc4[0][t][j] + facc4[1][t][j] + facc4[2][t][j] + facc4[3][t][j];
      atomicAdd(&fp[j], s + base[j]);
    }
  }
}

extern "C" void kernel_launch(void* const* d_in, const int* in_sizes, int n_in,
                              void* d_out, int out_size, void* d_ws, size_t ws_size,
                              hipStream_t stream) {
  const float* fea = (const float*)d_in[0];
  const float* Wl1 = (const float*)d_in[1];
  const float* bl1 = (const float*)d_in[2];
  const float* Wl2 = (const float*)d_in[3];
  const float* bl2 = (const float*)d_in[4];
  const float* Wc1 = (const float*)d_in[5];
  const float* bc1 = (const float*)d_in[6];
  const float* Wc2 = (const float*)d_in[7];
  const float* bc2 = (const float*)d_in[8];
  const float* Wc3 = (const float*)d_in[9];
  const float* bc3 = (const float*)d_in[10];
  float* xout = (float*)d_out;                // (8,1024,3)
  float* fine = (float*)d_out + 24576;        // (8,16384,3)
  char* ws = (char*)d_ws;
  float* h1  = (float*)ws;                    // 32 KB
  float* xf  = (float*)(ws + 32768);          // 96 KB
  float* gp  = (float*)(ws + 131072);         // 16 KB
  bf16*  W2T = (bf16*)(ws + 147456);          // 512 KB
  float* G   = (float*)(ws + 671744);         // 32 KB

  k_pre<<<1409, 256, 0, stream>>>(fea, Wl1, bl1, Wc1, bc1, Wc2, h1, gp, W2T, G, fine);
  k_lin2<<<192, 256, 0, stream>>>(h1, Wl2, bl2, xf, xout);
  k_gemm<<<2048, 512, 0, stream>>>(W2T, gp, G, Wc1, xf, bc2, Wc3, bc3, fine);
}